// Round 1
// baseline (253.301 us; speedup 1.0000x reference)
//
#include <hip/hip_runtime.h>
#include <hip/hip_bf16.h>

// Problem constants (from reference): N=500000, C=128, R=4 (C/R=32), B=32.
#define C 128
#define CR 32
#define B 32

// ---------------------------------------------------------------------------
// Kernel 1: segment sum + counts. batch is sorted, so each block's row range
// touches ~1-2 segments; accumulate in registers, flush via atomicAdd only on
// segment change. 128 threads = one column per thread (coalesced 512B/row).
// ---------------------------------------------------------------------------
__global__ __launch_bounds__(128) void seg_sum_kernel(
    const float* __restrict__ x, const int* __restrict__ batch,
    float* __restrict__ sums, float* __restrict__ counts,
    int N, int rows_per_block)
{
    const int t = threadIdx.x;                       // column 0..127
    long r0 = (long)blockIdx.x * rows_per_block;
    long r1 = r0 + rows_per_block;
    if (r1 > N) r1 = N;
    if (r0 >= r1) return;

    float acc = 0.0f;
    int   cnt = 0;
    int   curseg = batch[r0];

    for (long r = r0; r < r1; ++r) {
        int b = batch[r];                            // wave-uniform (broadcast)
        if (b != curseg) {                           // uniform branch
            atomicAdd(&sums[curseg * C + t], acc);
            if (t == 0) atomicAdd(&counts[curseg], (float)cnt);
            acc = 0.0f; cnt = 0; curseg = b;
        }
        acc += x[r * C + t];
        cnt++;
    }
    atomicAdd(&sums[curseg * C + t], acc);
    if (t == 0) atomicAdd(&counts[curseg], (float)cnt);
}

// ---------------------------------------------------------------------------
// Kernel 2: avg = sums/counts; h = relu(avg@W1 + b1); attn = sigmoid(h@W2+b2)
// Single block, 1024 threads. avg and h staged in LDS. W1 is [C][CR] row-major,
// W2 is [CR][C] row-major (matching jax layout).
// ---------------------------------------------------------------------------
__global__ __launch_bounds__(1024) void mlp_gate_kernel(
    const float* __restrict__ sums, const float* __restrict__ counts,
    const float* __restrict__ W1, const float* __restrict__ b1,
    const float* __restrict__ W2, const float* __restrict__ b2,
    float* __restrict__ attn)
{
    __shared__ float s_avg[B][C];
    __shared__ float s_h[B][CR];
    const int tid = threadIdx.x;

    // load avg: B*C = 4096 elements, 4 per thread
    for (int k = tid; k < B * C; k += 1024) {
        int g = k >> 7;                              // /C
        s_avg[g][k & (C - 1)] = sums[k] / fmaxf(counts[g], 1.0f);
    }
    __syncthreads();

    // h: B*CR = 1024 outputs, one per thread
    {
        int g = tid >> 5;                            // /CR
        int j = tid & (CR - 1);
        float d = b1[j];
        #pragma unroll 8
        for (int c = 0; c < C; ++c)
            d += s_avg[g][c] * W1[c * CR + j];       // avg: broadcast; W1: coalesced
        s_h[g][j] = fmaxf(d, 0.0f);
    }
    __syncthreads();

    // attn: B*C = 4096 outputs, 4 per thread
    for (int k = tid; k < B * C; k += 1024) {
        int g = k >> 7;
        int c = k & (C - 1);
        float d = b2[c];
        #pragma unroll
        for (int j = 0; j < CR; ++j)
            d += s_h[g][j] * W2[j * C + c];          // h: broadcast; W2: coalesced
        attn[k] = 1.0f / (1.0f + expf(-d));
    }
}

// ---------------------------------------------------------------------------
// Kernel 3: out[n][c] = x[n][c] * attn[batch[n]][c], float4-vectorized.
// attn is 16KB -> L1-resident; batch[row] is a wave-broadcast load.
// ---------------------------------------------------------------------------
__global__ __launch_bounds__(256) void scale_kernel(
    const float4* __restrict__ x4, const int* __restrict__ batch,
    const float4* __restrict__ attn4, float4* __restrict__ out4,
    long total4)
{
    long idx    = (long)blockIdx.x * blockDim.x + threadIdx.x;
    long stride = (long)gridDim.x * blockDim.x;
    for (; idx < total4; idx += stride) {
        long row = idx >> 5;                         // C/4 = 32 float4 per row
        int  c4  = (int)(idx & 31);
        int  b   = batch[row];
        float4 xv = x4[idx];
        float4 av = attn4[b * 32 + c4];
        float4 o;
        o.x = xv.x * av.x; o.y = xv.y * av.y;
        o.z = xv.z * av.z; o.w = xv.w * av.w;
        out4[idx] = o;
    }
}

extern "C" void kernel_launch(void* const* d_in, const int* in_sizes, int n_in,
                              void* d_out, int out_size, void* d_ws, size_t ws_size,
                              hipStream_t stream) {
    const float* x     = (const float*)d_in[0];
    const int*   batch = (const int*)d_in[1];
    // d_in[2] = batch_num scalar (known = 32, compile-time B)
    const float* W1 = (const float*)d_in[3];
    const float* b1 = (const float*)d_in[4];
    const float* W2 = (const float*)d_in[5];
    const float* b2 = (const float*)d_in[6];
    float* out = (float*)d_out;

    const int N = in_sizes[0] / C;

    // workspace layout (floats): sums[B*C]=4096 | counts[B] (padded to 64) | attn[B*C]
    float* sums   = (float*)d_ws;
    float* counts = sums + B * C;          // offset 4096
    float* attn   = counts + 64;           // offset 4160 floats = 16640 B (16B aligned)

    // zero the accumulators (ws is poisoned with 0xAA by the harness)
    hipMemsetAsync(d_ws, 0, (size_t)(B * C + 64) * sizeof(float), stream);

    const int rows_per_block = 256;
    const int nblocks = (N + rows_per_block - 1) / rows_per_block;
    seg_sum_kernel<<<nblocks, 128, 0, stream>>>(x, batch, sums, counts, N, rows_per_block);

    mlp_gate_kernel<<<1, 1024, 0, stream>>>(sums, counts, W1, b1, W2, b2, attn);

    const long total4 = (long)N * (C / 4);
    scale_kernel<<<2048, 256, 0, stream>>>((const float4*)x, batch,
                                           (const float4*)attn, (float4*)out, total4);
}